// Round 6
// baseline (206.621 us; speedup 1.0000x reference)
//
#include <hip/hip_runtime.h>
#include <math.h>

#define IN_CH 128
#define G4    512   // 4*IN
#define K1    256   // 2*IN

__device__ __forceinline__ float sigmoidf_(float v){ return 1.f/(1.f + expf(-v)); }

__device__ __forceinline__ float dot4_(float4 a, float4 b){
  return a.x*b.x + a.y*b.y + a.z*b.z + a.w*b.w;
}

// All-reduce-sum over each 16-lane group: 4 pure-DPP stages (VALU speed, no LDS pipe).
// After xor1,xor2 each quad is uniform, so row_half_mirror/row_mirror act as xor4/xor8.
__device__ __forceinline__ float reduce16_(float v){
  int t;
  t = __builtin_amdgcn_update_dpp(0, __float_as_int(v), 0xB1, 0xF, 0xF, true);   // quad_perm [1,0,3,2] = xor1
  v += __int_as_float(t);
  t = __builtin_amdgcn_update_dpp(0, __float_as_int(v), 0x4E, 0xF, 0xF, true);   // quad_perm [2,3,0,1] = xor2
  v += __int_as_float(t);
  t = __builtin_amdgcn_update_dpp(0, __float_as_int(v), 0x141, 0xF, 0xF, true);  // row_half_mirror = xor4
  v += __int_as_float(t);
  t = __builtin_amdgcn_update_dpp(0, __float_as_int(v), 0x140, 0xF, 0xF, true);  // row_mirror = xor8
  v += __int_as_float(t);
  return v;
}

__device__ __forceinline__ float swz16_(float v){
  return __int_as_float(__builtin_amdgcn_ds_swizzle(__float_as_int(v), 0x401F)); // lane ^ 16
}

// Prologue: transpose weights + segment bounds + step-0 LSTM collapse (bias-only).
__global__ void prologue_kernel(const float* __restrict__ w_ih, const float* __restrict__ w_hh,
                                float* __restrict__ wTih, float* __restrict__ wThh,
                                const int* __restrict__ batch, int N, int B, int* __restrict__ segs,
                                const float* __restrict__ b_ih, const float* __restrict__ b_hh,
                                float* __restrict__ h, float* __restrict__ c, float* __restrict__ qstar){
  int blk = blockIdx.x;
  if (blk < 512){                       // transpose: idx over G4*K1 = 131072
    int idx = blk*256 + threadIdx.x;
    { int g = idx / K1; int k = idx - g*K1; wTih[k*G4 + g] = w_ih[idx]; }
    if (idx < G4*IN_CH){ int g = idx / IN_CH; int k = idx - g*IN_CH; wThh[k*G4 + g] = w_hh[idx]; }
  } else if (blk < 517){                // seg bounds: b in [0, B]
    int b = (blk - 512)*256 + threadIdx.x;
    if (b > B) return;
    if (b == B){ segs[B] = N; return; }
    int lo = 0, hi = N;
    while (lo < hi){ int mid = (lo + hi) >> 1; if (batch[mid] < b) lo = mid + 1; else hi = mid; }
    segs[b] = lo;
  } else {                              // init0: idx over B*IN_CH = 131072
    int idx = (blk - 517)*256 + threadIdx.x;
    if (idx >= B*IN_CH) return;
    int b = idx >> 7, ch = idx & 127;
    float iv = sigmoidf_(b_ih[ch]           + b_hh[ch]);
    float gv = tanhf    (b_ih[2*IN_CH + ch] + b_hh[2*IN_CH + ch]);
    float ov = sigmoidf_(b_ih[3*IN_CH + ch] + b_hh[3*IN_CH + ch]);
    float cv = iv*gv;           // f*c_prev = 0
    float hv = ov*tanhf(cv);
    c[idx] = cv; h[idx] = hv;
    qstar[b*K1 + ch] = hv;
  }
}

// Fused LSTM step (steps 1,2): gates in LDS, then cell update + q-half write.
// One block of 512 threads per 8 batch rows; thread = gate index.
__global__ __launch_bounds__(512) void lstm_fused_kernel(
    const float* __restrict__ qstar_in, float* __restrict__ h, float* __restrict__ c,
    const float* __restrict__ wTih, const float* __restrict__ wThh,
    const float* __restrict__ b_ih, const float* __restrict__ b_hh,
    float* __restrict__ qstar_out){
  int g    = threadIdx.x;      // 0..511
  int row0 = blockIdx.x*8;
  __shared__ float qs[8][K1];
  __shared__ float hs[8][IN_CH];
  __shared__ float gs[8][G4];
  for (int t = g; t < 8*K1; t += 512){ int r = t >> 8; int k = t & 255; qs[r][k] = qstar_in[(row0+r)*K1 + k]; }
  for (int t = g; t < 8*IN_CH; t += 512){ int r = t >> 7; int k = t & 127; hs[r][k] = h[(row0+r)*IN_CH + k]; }
  __syncthreads();
  float bias = b_ih[g] + b_hh[g];
  float acc[8];
#pragma unroll
  for (int r = 0; r < 8; ++r) acc[r] = bias;
  for (int k4 = 0; k4 < K1/4; ++k4){
    float w0 = wTih[(4*k4+0)*G4 + g];
    float w1 = wTih[(4*k4+1)*G4 + g];
    float w2 = wTih[(4*k4+2)*G4 + g];
    float w3 = wTih[(4*k4+3)*G4 + g];
#pragma unroll
    for (int r = 0; r < 8; ++r){
      float4 q = *reinterpret_cast<const float4*>(&qs[r][4*k4]);
      acc[r] += q.x*w0 + q.y*w1 + q.z*w2 + q.w*w3;
    }
  }
  for (int k4 = 0; k4 < IN_CH/4; ++k4){
    float w0 = wThh[(4*k4+0)*G4 + g];
    float w1 = wThh[(4*k4+1)*G4 + g];
    float w2 = wThh[(4*k4+2)*G4 + g];
    float w3 = wThh[(4*k4+3)*G4 + g];
#pragma unroll
    for (int r = 0; r < 8; ++r){
      float4 hv = *reinterpret_cast<const float4*>(&hs[r][4*k4]);
      acc[r] += hv.x*w0 + hv.y*w1 + hv.z*w2 + hv.w*w3;
    }
  }
#pragma unroll
  for (int r = 0; r < 8; ++r) gs[r][g] = acc[r];
  __syncthreads();
  for (int t = g; t < 8*IN_CH; t += 512){
    int r = t >> 7, ch = t & 127;
    int idx = (row0+r)*IN_CH + ch;
    float iv = sigmoidf_(gs[r][ch]);
    float fv = sigmoidf_(gs[r][IN_CH + ch]);
    float gv = tanhf(gs[r][2*IN_CH + ch]);
    float ov = sigmoidf_(gs[r][3*IN_CH + ch]);
    float cv = fv*c[idx] + iv*gv;
    float hv = ov*tanhf(cv);
    c[idx] = cv; h[idx] = hv;
    qstar_out[(row0+r)*K1 + ch] = hv;
  }
}

// Single-pass online-softmax weighted readout. One block per segment (no partials).
// 16 lanes per row (8 channels/lane), pure-DPP 16-lane reduce, deferred-max rescale,
// software-pipelined loads. Writes r-half of q_star directly.
__global__ __launch_bounds__(256) void attn_kernel(const float* __restrict__ x,
    float* __restrict__ qstar, const int* __restrict__ segs){
  int b = blockIdx.x;
  int s = segs[b], ce = segs[b+1];
  int tid = threadIdx.x;
  int wave = tid >> 6, lane = tid & 63;
  int grp = (lane >> 4) & 3, l16 = lane & 15;
  int sid = wave*4 + grp;           // 16 streams per block, 2 rows each, stride 32
  const float4 z4 = make_float4(0.f,0.f,0.f,0.f);
  const float4* x4 = reinterpret_cast<const float4*>(x);
  const float4* q4 = reinterpret_cast<const float4*>(&qstar[(size_t)b*K1]);
  float4 qa = q4[l16], qb = q4[16 + l16];   // channels l16*4..+3 and 64+l16*4..+3

  float m = -INFINITY, d = 0.f;
  float4 ra = z4, rb = z4;

  int j = s + sid*2;
  float4 a0 = z4, b0 = z4, a1 = z4, b1 = z4;
  if (j < ce){
    const float4* r0 = x4 + (size_t)j*(IN_CH/4);
    a0 = r0[l16]; b0 = r0[16 + l16];
    if (j + 1 < ce){ a1 = r0[32 + l16]; b1 = r0[48 + l16]; }
  }
  while (j < ce){
    int jn = j + 32;
    float4 na0 = z4, nb0 = z4, na1 = z4, nb1 = z4;
    if (jn < ce){                    // prefetch next pair while computing current
      const float4* rn = x4 + (size_t)jn*(IN_CH/4);
      na0 = rn[l16]; nb0 = rn[16 + l16];
      if (jn + 1 < ce){ na1 = rn[32 + l16]; nb1 = rn[48 + l16]; }
    }
    bool ok1 = (j + 1 < ce);
    float e0 = dot4_(a0, qa) + dot4_(b0, qb);
    float e1 = dot4_(a1, qa) + dot4_(b1, qb);
    e0 = reduce16_(e0);
    e1 = reduce16_(e1);
    e1 = ok1 ? e1 : -INFINITY;
    float em = fmaxf(e0, e1);
    if (em > m){                     // group-uniform; rarely taken after warmup
      float corr = __expf(m - em);   // m=-inf first time -> corr=0 zeroes state
      d *= corr;
      ra.x *= corr; ra.y *= corr; ra.z *= corr; ra.w *= corr;
      rb.x *= corr; rb.y *= corr; rb.z *= corr; rb.w *= corr;
      m = em;
    }
    float p0 = __expf(e0 - m);
    float p1 = __expf(e1 - m);
    d += p0 + p1;
    ra.x += p0*a0.x + p1*a1.x; ra.y += p0*a0.y + p1*a1.y;
    ra.z += p0*a0.z + p1*a1.z; ra.w += p0*a0.w + p1*a1.w;
    rb.x += p0*b0.x + p1*b1.x; rb.y += p0*b0.y + p1*b1.y;
    rb.z += p0*b0.z + p1*b1.z; rb.w += p0*b0.w + p1*b1.w;
    j = jn;
    a0 = na0; b0 = nb0; a1 = na1; b1 = nb1;
  }
  // merge group pairs: lane^16 (ds_swizzle), then lane^32 (shfl)
  {
    float mo = swz16_(m), dd = swz16_(d);
    float4 rao, rbo;
    rao.x = swz16_(ra.x); rao.y = swz16_(ra.y); rao.z = swz16_(ra.z); rao.w = swz16_(ra.w);
    rbo.x = swz16_(rb.x); rbo.y = swz16_(rb.y); rbo.z = swz16_(rb.z); rbo.w = swz16_(rb.w);
    float mn = fmaxf(m, mo);
    float c1 = (mn == -INFINITY) ? 0.f : __expf(m - mn);
    float c2 = (mn == -INFINITY) ? 0.f : __expf(mo - mn);
    d = d*c1 + dd*c2;
    ra.x = ra.x*c1 + rao.x*c2; ra.y = ra.y*c1 + rao.y*c2;
    ra.z = ra.z*c1 + rao.z*c2; ra.w = ra.w*c1 + rao.w*c2;
    rb.x = rb.x*c1 + rbo.x*c2; rb.y = rb.y*c1 + rbo.y*c2;
    rb.z = rb.z*c1 + rbo.z*c2; rb.w = rb.w*c1 + rbo.w*c2;
    m = mn;
  }
  {
    float mo = __shfl_xor(m, 32), dd = __shfl_xor(d, 32);
    float4 rao, rbo;
    rao.x = __shfl_xor(ra.x, 32); rao.y = __shfl_xor(ra.y, 32);
    rao.z = __shfl_xor(ra.z, 32); rao.w = __shfl_xor(ra.w, 32);
    rbo.x = __shfl_xor(rb.x, 32); rbo.y = __shfl_xor(rb.y, 32);
    rbo.z = __shfl_xor(rb.z, 32); rbo.w = __shfl_xor(rb.w, 32);
    float mn = fmaxf(m, mo);
    float c1 = (mn == -INFINITY) ? 0.f : __expf(m - mn);
    float c2 = (mn == -INFINITY) ? 0.f : __expf(mo - mn);
    d = d*c1 + dd*c2;
    ra.x = ra.x*c1 + rao.x*c2; ra.y = ra.y*c1 + rao.y*c2;
    ra.z = ra.z*c1 + rao.z*c2; ra.w = ra.w*c1 + rao.w*c2;
    rb.x = rb.x*c1 + rbo.x*c2; rb.y = rb.y*c1 + rbo.y*c2;
    rb.z = rb.z*c1 + rbo.z*c2; rb.w = rb.w*c1 + rbo.w*c2;
    m = mn;
  }
  __shared__ float mbuf[4], dbuf[4];
  __shared__ float rbA[4][64], rbB[4][64];
  if (lane < 16){
    *reinterpret_cast<float4*>(&rbA[wave][l16*4]) = ra;
    *reinterpret_cast<float4*>(&rbB[wave][l16*4]) = rb;
    if (l16 == 0){ mbuf[wave] = m; dbuf[wave] = d; }
  }
  __syncthreads();
  if (tid < IN_CH){
    float M = fmaxf(fmaxf(mbuf[0], mbuf[1]), fmaxf(mbuf[2], mbuf[3]));
    float f0 = (M == -INFINITY) ? 0.f : __expf(mbuf[0] - M);
    float f1 = (M == -INFINITY) ? 0.f : __expf(mbuf[1] - M);
    float f2 = (M == -INFINITY) ? 0.f : __expf(mbuf[2] - M);
    float f3 = (M == -INFINITY) ? 0.f : __expf(mbuf[3] - M);
    float v0 = (tid < 64) ? rbA[0][tid] : rbB[0][tid-64];
    float v1 = (tid < 64) ? rbA[1][tid] : rbB[1][tid-64];
    float v2 = (tid < 64) ? rbA[2][tid] : rbB[2][tid-64];
    float v3 = (tid < 64) ? rbA[3][tid] : rbB[3][tid-64];
    float R = v0*f0 + v1*f1 + v2*f2 + v3*f3;
    float D = dbuf[0]*f0 + dbuf[1]*f1 + dbuf[2]*f2 + dbuf[3]*f3;
    qstar[(size_t)b*K1 + IN_CH + tid] = (D > 0.f) ? R/D : 0.f;
  }
}

extern "C" void kernel_launch(void* const* d_in, const int* in_sizes, int n_in,
                              void* d_out, int out_size, void* d_ws, size_t ws_size,
                              hipStream_t stream){
  const float* x     = (const float*)d_in[0];
  const float* w_ih  = (const float*)d_in[1];
  const float* w_hh  = (const float*)d_in[2];
  const float* b_ih  = (const float*)d_in[3];
  const float* b_hh  = (const float*)d_in[4];
  const int*   batch = (const int*)d_in[5];
  int N = in_sizes[0] / IN_CH;
  int B = out_size / K1;
  float* out = (float*)d_out;   // q_star lives here

  float* ws    = (float*)d_ws;
  float* h     = ws;                    // B*128
  float* c     = h + (size_t)B*IN_CH;   // B*128
  float* wTih  = c + (size_t)B*IN_CH;   // 256*512
  float* wThh  = wTih + K1*G4;          // 128*512
  int*   segs  = (int*)(wThh + IN_CH*G4);      // B+1

  prologue_kernel<<<517 + (B*IN_CH + 255)/256, 256, 0, stream>>>(
      w_ih, w_hh, wTih, wThh, batch, N, B, segs, b_ih, b_hh, h, c, out);

  attn_kernel<<<B, 256, 0, stream>>>(x, out, segs);
  for (int step = 1; step < 3; ++step){
    lstm_fused_kernel<<<B/8, 512, 0, stream>>>(out, h, c, wTih, wThh, b_ih, b_hh, out);
    attn_kernel<<<B, 256, 0, stream>>>(x, out, segs);
  }
}

// Round 7
// 197.995 us; speedup vs baseline: 1.0436x; 1.0436x over previous
//
#include <hip/hip_runtime.h>
#include <math.h>

#define IN_CH 128
#define G4    512   // 4*IN
#define K1    256   // 2*IN

__device__ __forceinline__ float sigmoidf_(float v){ return 1.f/(1.f + expf(-v)); }

__device__ __forceinline__ float dot4_(float4 a, float4 b){
  return a.x*b.x + a.y*b.y + a.z*b.z + a.w*b.w;
}

// All-reduce-sum over each 8-lane group: 3 pure-DPP stages (VALU speed, no LDS pipe).
// After xor1,xor2 each quad is uniform, so row_half_mirror acts as xor4.
__device__ __forceinline__ float reduce8_(float v){
  int t;
  t = __builtin_amdgcn_update_dpp(0, __float_as_int(v), 0xB1, 0xF, 0xF, true);   // quad_perm [1,0,3,2] = xor1
  v += __int_as_float(t);
  t = __builtin_amdgcn_update_dpp(0, __float_as_int(v), 0x4E, 0xF, 0xF, true);   // quad_perm [2,3,0,1] = xor2
  v += __int_as_float(t);
  t = __builtin_amdgcn_update_dpp(0, __float_as_int(v), 0x141, 0xF, 0xF, true);  // row_half_mirror = xor4
  v += __int_as_float(t);
  return v;
}

__device__ __forceinline__ float swz8_(float v){
  return __int_as_float(__builtin_amdgcn_ds_swizzle(__float_as_int(v), 0x201F)); // lane ^ 8
}
__device__ __forceinline__ float swz16_(float v){
  return __int_as_float(__builtin_amdgcn_ds_swizzle(__float_as_int(v), 0x401F)); // lane ^ 16
}

// Prologue: transpose weights + segment bounds + step-0 LSTM collapse (bias-only).
__global__ void prologue_kernel(const float* __restrict__ w_ih, const float* __restrict__ w_hh,
                                float* __restrict__ wTih, float* __restrict__ wThh,
                                const int* __restrict__ batch, int N, int B, int* __restrict__ segs,
                                const float* __restrict__ b_ih, const float* __restrict__ b_hh,
                                float* __restrict__ h, float* __restrict__ c, float* __restrict__ qstar){
  int blk = blockIdx.x;
  if (blk < 512){                       // transpose: idx over G4*K1 = 131072
    int idx = blk*256 + threadIdx.x;
    { int g = idx / K1; int k = idx - g*K1; wTih[k*G4 + g] = w_ih[idx]; }
    if (idx < G4*IN_CH){ int g = idx / IN_CH; int k = idx - g*IN_CH; wThh[k*G4 + g] = w_hh[idx]; }
  } else if (blk < 517){                // seg bounds: b in [0, B]
    int b = (blk - 512)*256 + threadIdx.x;
    if (b > B) return;
    if (b == B){ segs[B] = N; return; }
    int lo = 0, hi = N;
    while (lo < hi){ int mid = (lo + hi) >> 1; if (batch[mid] < b) lo = mid + 1; else hi = mid; }
    segs[b] = lo;
  } else {                              // init0: idx over B*IN_CH = 131072
    int idx = (blk - 517)*256 + threadIdx.x;
    if (idx >= B*IN_CH) return;
    int b = idx >> 7, ch = idx & 127;
    float iv = sigmoidf_(b_ih[ch]           + b_hh[ch]);
    float gv = tanhf    (b_ih[2*IN_CH + ch] + b_hh[2*IN_CH + ch]);
    float ov = sigmoidf_(b_ih[3*IN_CH + ch] + b_hh[3*IN_CH + ch]);
    float cv = iv*gv;           // f*c_prev = 0
    float hv = ov*tanhf(cv);
    c[idx] = cv; h[idx] = hv;
    qstar[b*K1 + ch] = hv;
  }
}

// Fused LSTM step (steps 1,2): gates in LDS, then cell update + q-half write.
// One block of 512 threads per 8 batch rows; thread = gate index.
__global__ __launch_bounds__(512) void lstm_fused_kernel(
    const float* __restrict__ qstar_in, float* __restrict__ h, float* __restrict__ c,
    const float* __restrict__ wTih, const float* __restrict__ wThh,
    const float* __restrict__ b_ih, const float* __restrict__ b_hh,
    float* __restrict__ qstar_out){
  int g    = threadIdx.x;      // 0..511
  int row0 = blockIdx.x*8;
  __shared__ float qs[8][K1];
  __shared__ float hs[8][IN_CH];
  __shared__ float gs[8][G4];
  for (int t = g; t < 8*K1; t += 512){ int r = t >> 8; int k = t & 255; qs[r][k] = qstar_in[(row0+r)*K1 + k]; }
  for (int t = g; t < 8*IN_CH; t += 512){ int r = t >> 7; int k = t & 127; hs[r][k] = h[(row0+r)*IN_CH + k]; }
  __syncthreads();
  float bias = b_ih[g] + b_hh[g];
  float acc[8];
#pragma unroll
  for (int r = 0; r < 8; ++r) acc[r] = bias;
  for (int k4 = 0; k4 < K1/4; ++k4){
    float w0 = wTih[(4*k4+0)*G4 + g];
    float w1 = wTih[(4*k4+1)*G4 + g];
    float w2 = wTih[(4*k4+2)*G4 + g];
    float w3 = wTih[(4*k4+3)*G4 + g];
#pragma unroll
    for (int r = 0; r < 8; ++r){
      float4 q = *reinterpret_cast<const float4*>(&qs[r][4*k4]);
      acc[r] += q.x*w0 + q.y*w1 + q.z*w2 + q.w*w3;
    }
  }
  for (int k4 = 0; k4 < IN_CH/4; ++k4){
    float w0 = wThh[(4*k4+0)*G4 + g];
    float w1 = wThh[(4*k4+1)*G4 + g];
    float w2 = wThh[(4*k4+2)*G4 + g];
    float w3 = wThh[(4*k4+3)*G4 + g];
#pragma unroll
    for (int r = 0; r < 8; ++r){
      float4 hv = *reinterpret_cast<const float4*>(&hs[r][4*k4]);
      acc[r] += hv.x*w0 + hv.y*w1 + hv.z*w2 + hv.w*w3;
    }
  }
#pragma unroll
  for (int r = 0; r < 8; ++r) gs[r][g] = acc[r];
  __syncthreads();
  for (int t = g; t < 8*IN_CH; t += 512){
    int r = t >> 7, ch = t & 127;
    int idx = (row0+r)*IN_CH + ch;
    float iv = sigmoidf_(gs[r][ch]);
    float fv = sigmoidf_(gs[r][IN_CH + ch]);
    float gv = tanhf(gs[r][2*IN_CH + ch]);
    float ov = sigmoidf_(gs[r][3*IN_CH + ch]);
    float cv = fv*c[idx] + iv*gv;
    float hv = ov*tanhf(cv);
    c[idx] = cv; h[idx] = hv;
    qstar_out[(row0+r)*K1 + ch] = hv;
  }
}

// Single-pass online-softmax weighted readout. One block per segment.
// 8 lanes per row (16 channels/lane as 4 float4), pure-DPP 8-lane reduce,
// depth-2 branchless clamped prefetch, max-growth rescale.
__global__ __launch_bounds__(256) void attn_kernel(const float* __restrict__ x,
    float* __restrict__ qstar, const int* __restrict__ segs){
  int b = blockIdx.x;
  int s = segs[b], ce = segs[b+1];
  int jmax = (ce > 0) ? (ce - 1) : 0;
  int tid = threadIdx.x;
  int wave = tid >> 6, lane = tid & 63;
  int grp = lane >> 3, l8 = lane & 7;
  int sid = wave*8 + grp;           // 32 streams per block, 1 row each, stride 32
  const float4 z4 = make_float4(0.f,0.f,0.f,0.f);
  const float4* x4 = reinterpret_cast<const float4*>(x);
  const float4* q4 = reinterpret_cast<const float4*>(&qstar[(size_t)b*K1]);
  // lane's 16 channels: {4*l8.., 32+4*l8.., 64+4*l8.., 96+4*l8..}
  float4 q0 = q4[l8], q1 = q4[8 + l8], q2 = q4[16 + l8], q3 = q4[24 + l8];

  float m = -INFINITY, d = 0.f;
  float4 ra = z4, rb = z4, rc = z4, rd = z4;

  int j = s + sid;
  float4 A0, A1, A2, A3, B0, B1, B2, B3;
  {
    int jc0 = (j      < ce) ? j      : jmax;   // clamped: always a legal row
    int jc1 = (j + 32 < ce) ? j + 32 : jmax;
    const float4* r0 = x4 + (size_t)jc0*(IN_CH/4);
    const float4* r1 = x4 + (size_t)jc1*(IN_CH/4);
    A0 = r0[l8]; A1 = r0[8 + l8]; A2 = r0[16 + l8]; A3 = r0[24 + l8];
    B0 = r1[l8]; B1 = r1[8 + l8]; B2 = r1[16 + l8]; B3 = r1[24 + l8];
  }
  for (; j < ce; j += 32){
    // branchless prefetch for j+64 (clamped; issued before the dependent chain)
    int jn = j + 64;
    int jc = (jn < ce) ? jn : jmax;
    const float4* rp = x4 + (size_t)jc*(IN_CH/4);
    float4 C0 = rp[l8], C1 = rp[8 + l8], C2 = rp[16 + l8], C3 = rp[24 + l8];

    float e = dot4_(A0, q0) + dot4_(A1, q1) + dot4_(A2, q2) + dot4_(A3, q3);
    e = reduce8_(e);                 // group-uniform row score
    if (e > m){                      // new running max (group-uniform predicate)
      float corr = __expf(m - e);    // m=-inf first time -> corr=0 zeroes state
      d *= corr;
      ra.x *= corr; ra.y *= corr; ra.z *= corr; ra.w *= corr;
      rb.x *= corr; rb.y *= corr; rb.z *= corr; rb.w *= corr;
      rc.x *= corr; rc.y *= corr; rc.z *= corr; rc.w *= corr;
      rd.x *= corr; rd.y *= corr; rd.z *= corr; rd.w *= corr;
      m = e;
    }
    float p = __expf(e - m);
    d += p;
    ra.x += p*A0.x; ra.y += p*A0.y; ra.z += p*A0.z; ra.w += p*A0.w;
    rb.x += p*A1.x; rb.y += p*A1.y; rb.z += p*A1.z; rb.w += p*A1.w;
    rc.x += p*A2.x; rc.y += p*A2.y; rc.z += p*A2.z; rc.w += p*A2.w;
    rd.x += p*A3.x; rd.y += p*A3.y; rd.z += p*A3.z; rd.w += p*A3.w;
    A0 = B0; A1 = B1; A2 = B2; A3 = B3;
    B0 = C0; B1 = C1; B2 = C2; B3 = C3;
  }

  // merge streams: lane^8, lane^16 (ds_swizzle), lane^32 (shfl)
#define MERGE_STAGE(GET)                                                        \
  {                                                                             \
    float mo = GET(m), dd = GET(d);                                             \
    float4 sa, sb, sc, sd;                                                      \
    sa.x = GET(ra.x); sa.y = GET(ra.y); sa.z = GET(ra.z); sa.w = GET(ra.w);     \
    sb.x = GET(rb.x); sb.y = GET(rb.y); sb.z = GET(rb.z); sb.w = GET(rb.w);     \
    sc.x = GET(rc.x); sc.y = GET(rc.y); sc.z = GET(rc.z); sc.w = GET(rc.w);     \
    sd.x = GET(rd.x); sd.y = GET(rd.y); sd.z = GET(rd.z); sd.w = GET(rd.w);     \
    float mn = fmaxf(m, mo);                                                    \
    float c1 = (mn == -INFINITY) ? 0.f : __expf(m - mn);                        \
    float c2 = (mn == -INFINITY) ? 0.f : __expf(mo - mn);                       \
    d = d*c1 + dd*c2;                                                           \
    ra.x = ra.x*c1 + sa.x*c2; ra.y = ra.y*c1 + sa.y*c2;                         \
    ra.z = ra.z*c1 + sa.z*c2; ra.w = ra.w*c1 + sa.w*c2;                         \
    rb.x = rb.x*c1 + sb.x*c2; rb.y = rb.y*c1 + sb.y*c2;                         \
    rb.z = rb.z*c1 + sb.z*c2; rb.w = rb.w*c1 + sb.w*c2;                         \
    rc.x = rc.x*c1 + sc.x*c2; rc.y = rc.y*c1 + sc.y*c2;                         \
    rc.z = rc.z*c1 + sc.z*c2; rc.w = rc.w*c1 + sc.w*c2;                         \
    rd.x = rd.x*c1 + sd.x*c2; rd.y = rd.y*c1 + sd.y*c2;                         \
    rd.z = rd.z*c1 + sd.z*c2; rd.w = rd.w*c1 + sd.w*c2;                         \
    m = mn;                                                                     \
  }
#define SHFL32(v) __shfl_xor((v), 32)
  MERGE_STAGE(swz8_)
  MERGE_STAGE(swz16_)
  MERGE_STAGE(SHFL32)
#undef MERGE_STAGE
#undef SHFL32

  __shared__ float mbuf[4], dbuf[4];
  __shared__ float rbuf[4][IN_CH];
  if (lane < 8){
    *reinterpret_cast<float4*>(&rbuf[wave][ 0 + lane*4]) = ra;
    *reinterpret_cast<float4*>(&rbuf[wave][32 + lane*4]) = rb;
    *reinterpret_cast<float4*>(&rbuf[wave][64 + lane*4]) = rc;
    *reinterpret_cast<float4*>(&rbuf[wave][96 + lane*4]) = rd;
    if (lane == 0){ mbuf[wave] = m; dbuf[wave] = d; }
  }
  __syncthreads();
  if (tid < IN_CH){
    float M = fmaxf(fmaxf(mbuf[0], mbuf[1]), fmaxf(mbuf[2], mbuf[3]));
    float f0 = (M == -INFINITY) ? 0.f : __expf(mbuf[0] - M);
    float f1 = (M == -INFINITY) ? 0.f : __expf(mbuf[1] - M);
    float f2 = (M == -INFINITY) ? 0.f : __expf(mbuf[2] - M);
    float f3 = (M == -INFINITY) ? 0.f : __expf(mbuf[3] - M);
    float R = rbuf[0][tid]*f0 + rbuf[1][tid]*f1 + rbuf[2][tid]*f2 + rbuf[3][tid]*f3;
    float D = dbuf[0]*f0 + dbuf[1]*f1 + dbuf[2]*f2 + dbuf[3]*f3;
    qstar[(size_t)b*K1 + IN_CH + tid] = (D > 0.f) ? R/D : 0.f;
  }
}

extern "C" void kernel_launch(void* const* d_in, const int* in_sizes, int n_in,
                              void* d_out, int out_size, void* d_ws, size_t ws_size,
                              hipStream_t stream){
  const float* x     = (const float*)d_in[0];
  const float* w_ih  = (const float*)d_in[1];
  const float* w_hh  = (const float*)d_in[2];
  const float* b_ih  = (const float*)d_in[3];
  const float* b_hh  = (const float*)d_in[4];
  const int*   batch = (const int*)d_in[5];
  int N = in_sizes[0] / IN_CH;
  int B = out_size / K1;
  float* out = (float*)d_out;   // q_star lives here

  float* ws    = (float*)d_ws;
  float* h     = ws;                    // B*128
  float* c     = h + (size_t)B*IN_CH;   // B*128
  float* wTih  = c + (size_t)B*IN_CH;   // 256*512
  float* wThh  = wTih + K1*G4;          // 128*512
  int*   segs  = (int*)(wThh + IN_CH*G4);      // B+1

  prologue_kernel<<<517 + (B*IN_CH + 255)/256, 256, 0, stream>>>(
      w_ih, w_hh, wTih, wThh, batch, N, B, segs, b_ih, b_hh, h, c, out);

  attn_kernel<<<B, 256, 0, stream>>>(x, out, segs);
  for (int step = 1; step < 3; ++step){
    lstm_fused_kernel<<<B/8, 512, 0, stream>>>(out, h, c, wTih, wThh, b_ih, b_hh, out);
    attn_kernel<<<B, 256, 0, stream>>>(x, out, segs);
  }
}